// Round 6
// baseline (103.560 us; speedup 1.0000x reference)
//
#include <hip/hip_runtime.h>

#define D_ 1024
#define H_ 16
#define HKV_ 4
#define B_ 2
#define S_ 1024
#define BS_ (B_*S_)
#define QKVW 1536
#define QB 64
#define NC (S_/QB)

typedef short bf8 __attribute__((ext_vector_type(8)));
typedef float f32x4 __attribute__((ext_vector_type(4)));

#define MFMA_B16(a,b,c) __builtin_amdgcn_mfma_f32_16x16x32_bf16((a),(b),(c),0,0,0)

// async global->LDS, 16B per lane; LDS dest must be linear in lane order
#define GLOAD16(g, l) __builtin_amdgcn_global_load_lds( \
    (const __attribute__((address_space(1))) void*)(g), \
    (__attribute__((address_space(3))) void*)(l), 16, 0, 0)

// LDS XOR swizzle for [64][64] bf16 tiles: flips 16B-unit within 8-row stripe.
#define SW(row, idx) ((idx) ^ (((row) & 7) << 3))

__device__ __forceinline__ unsigned short f2b(float f) {
  unsigned int u = __float_as_uint(f);
  u += 0x7FFFu + ((u >> 16) & 1u);
  return (unsigned short)(u >> 16);
}
__device__ __forceinline__ float b2f(unsigned short h) {
  return __uint_as_float(((unsigned int)h) << 16);
}
__device__ __forceinline__ float feat(float x) { return x > 0.f ? x + 1.f : __expf(x); }

// ---------- helpers used by the fused prep kernel ----------
__device__ __forceinline__ void conv_body(const float* __restrict__ src,
                                          unsigned short* __restrict__ dst,
                                          int sub, int n4, int tid) {
  int i = sub * 256 + tid;
  if (i >= n4) return;
  float4 v = ((const float4*)src)[i];
  ushort4 o;
  o.x = f2b(v.x); o.y = f2b(v.y); o.z = f2b(v.z); o.w = f2b(v.w);
  ((ushort4*)dst)[i] = o;
}

__device__ __forceinline__ void tconv_body(const float* __restrict__ src,
                                           unsigned short* __restrict__ dst,
                                           int bx, int by, int ss, int ds,
                                           int tid, float (*tl)[65]) {
  int r0 = by * 64, c0 = bx * 64;
  int ty = tid >> 4, tx4 = (tid & 15) * 4;
#pragma unroll
  for (int rep = 0; rep < 4; ++rep) {
    int r = ty + rep * 16;
    float4 v = *(const float4*)&src[(size_t)(r0 + r) * ss + c0 + tx4];
    tl[r][tx4] = v.x; tl[r][tx4 + 1] = v.y; tl[r][tx4 + 2] = v.z; tl[r][tx4 + 3] = v.w;
  }
  __syncthreads();
#pragma unroll
  for (int rep = 0; rep < 4; ++rep) {
    int c = ty + rep * 16;
    ushort4 o;
    o.x = f2b(tl[tx4 + 0][c]); o.y = f2b(tl[tx4 + 1][c]);
    o.z = f2b(tl[tx4 + 2][c]); o.w = f2b(tl[tx4 + 3][c]);
    *(ushort4*)&dst[(size_t)(c0 + c) * ds + r0 + tx4] = o;
  }
}

// ---------- P1: all independent elementwise/transpose prep in one kernel ----------
__global__ __launch_bounds__(256) void k_prep(const float* __restrict__ x,
                                              const float* __restrict__ Wq,
                                              const float* __restrict__ Wo,
                                              const float* __restrict__ Wk,
                                              const float* __restrict__ Wv,
                                              const float* __restrict__ Wc,
                                              const float* __restrict__ We,
                                              unsigned short* __restrict__ xb,
                                              unsigned short* __restrict__ Wqkv_t,
                                              unsigned short* __restrict__ Wo_t,
                                              unsigned short* __restrict__ Wkv_b,
                                              unsigned short* __restrict__ Wc_b,
                                              unsigned short* __restrict__ We_t) {
  __shared__ float tl[64][65];
  int blk = blockIdx.x, tid = threadIdx.x;
  if (blk < 2048) {
    conv_body(x, xb, blk, BS_ * D_ / 4, tid);
  } else if (blk < 2304) {
    conv_body(Wk, Wkv_b, blk - 2048, 1024 * 256 / 4, tid);
  } else if (blk < 2560) {
    conv_body(Wv, Wkv_b + 1024 * 256, blk - 2304, 1024 * 256 / 4, tid);
  } else if (blk < 2816) {
    int sb = blk - 2560;
    tconv_body(Wq, Wqkv_t, sb & 15, sb >> 4, 1024, 1024, tid, tl);
  } else if (blk < 3072) {
    int sb = blk - 2816;
    tconv_body(Wo, Wo_t, sb & 15, sb >> 4, 1024, 1024, tid, tl);
  } else if (blk < 3088) {
    conv_body(Wc, Wc_b, blk - 3072, 256 * 64 / 4, tid);
  } else {
    tconv_body(We, We_t, blk - 3088, 0, 256, 64, tid, tl);
  }
}

// ---------- bt-GEMM core, 64x128 tile, 2 waves, BK=32, global_load_lds ----------
// MODE 0: f32 out + bias                     (O-proj)
// MODE 1: bf16 out + bias + feat on col<1280 (QKV -> qkvb)
// MODE 2: foldKV bf16 remap out; blockIdx.y==4 -> fused bias fold
// MODE 3: T-both: f32 C + bf16 transposed C2
template<int MODE>
__global__ __launch_bounds__(128) void k_gemm(const unsigned short* __restrict__ A,
                                              const unsigned short* __restrict__ Bt,
                                              const float* __restrict__ bias,
                                              void* __restrict__ C,
                                              void* __restrict__ C2,
                                              int N, int K,
                                              const float* __restrict__ fbq,
                                              const float* __restrict__ fbk,
                                              const float* __restrict__ fbv,
                                              const float* __restrict__ fWce) {
  if (MODE == 2 && blockIdx.y == 4) {
    // fused qkv bias: [bq | bk@Wce | bv@Wce]
    int t = blockIdx.x * 128 + threadIdx.x;
    if (t >= QKVW) return;
    float* biasq = (float*)C2;
    if (t < 1024) { biasq[t] = fbq[t]; return; }
    const float* b = (t < 1280) ? fbk : fbv;
    int n = (t < 1280) ? (t - 1024) : (t - 1280);
    float s = 0.f;
    for (int j = 0; j < 256; ++j) s += b[j] * fWce[j * 256 + n];
    biasq[t] = s;
    return;
  }
  __shared__ __align__(16) unsigned short As[64 * 32];
  __shared__ __align__(16) unsigned short Bs[128 * 32];
  const int tid = threadIdx.x;
  const int lane = tid & 63, wave = tid >> 6;
  const int row0 = blockIdx.y * 64, col0 = blockIdx.x * 128;
  const f32x4 fzero = {0.f, 0.f, 0.f, 0.f};
  f32x4 acc[4][4];
#pragma unroll
  for (int i = 0; i < 4; ++i)
#pragma unroll
    for (int j = 0; j < 4; ++j) acc[i][j] = fzero;
  const int lr = lane & 15, lq = lane >> 4, lk = lq * 8;
  for (int k0 = 0; k0 < K; k0 += 32) {
#pragma unroll
    for (int i = 0; i < 2; ++i) {
      int e = (tid + i * 128) * 8;
      int r = e >> 5, c = e & 31;
      GLOAD16(&A[(size_t)(row0 + r) * K + k0 + c], &As[e]);
    }
#pragma unroll
    for (int i = 0; i < 4; ++i) {
      int e = (tid + i * 128) * 8;
      int r = e >> 5, c = e & 31;
      GLOAD16(&Bt[(size_t)(col0 + r) * K + k0 + c], &Bs[e]);
    }
    __syncthreads();
    bf8 af[4], bfr[4];
#pragma unroll
    for (int mi = 0; mi < 4; ++mi)
      af[mi] = *(const bf8*)&As[(mi * 16 + lr) * 32 + lk];
#pragma unroll
    for (int ni = 0; ni < 4; ++ni)
      bfr[ni] = *(const bf8*)&Bs[(wave * 64 + ni * 16 + lr) * 32 + lk];
#pragma unroll
    for (int mi = 0; mi < 4; ++mi)
#pragma unroll
      for (int ni = 0; ni < 4; ++ni)
        acc[mi][ni] = MFMA_B16(af[mi], bfr[ni], acc[mi][ni]);
    __syncthreads();
  }
#pragma unroll
  for (int mi = 0; mi < 4; ++mi)
#pragma unroll
    for (int ni = 0; ni < 4; ++ni) {
      int col = col0 + wave * 64 + ni * 16 + lr;
      float bv = (MODE == 0 || MODE == 1) ? bias[col] : 0.f;
#pragma unroll
      for (int r = 0; r < 4; ++r) {
        int row = row0 + mi * 16 + lq * 4 + r;
        float v = acc[mi][ni][r] + bv;
        if (MODE == 0) {
          ((float*)C)[(size_t)row * N + col] = v;
        } else if (MODE == 1) {
          if (col < 1280) v = feat(v);   // pre-feat Q and K sections
          ((unsigned short*)C)[(size_t)row * N + col] = f2b(v);
        } else if (MODE == 2) {
          int sec = col >> 10, cc = col & 1023;
          ((unsigned short*)C)[(size_t)(1024 + sec * 256 + row) * 1024 + cc] = f2b(v);
        } else {  // MODE 3
          ((float*)C)[(size_t)row * 256 + col] = v;
          ((unsigned short*)C2)[(size_t)col * 256 + row] = f2b(v);
        }
      }
    }
}

// ---------- fused V-transpose + per-chunk KV sums (qkvb bf16, K pre-featted) ----------
__global__ __launch_bounds__(256) void k_vkv(const unsigned short* __restrict__ qkvb,
                                             unsigned short* __restrict__ vt,
                                             float* __restrict__ stc) {
  __shared__ unsigned short tl[64][72];   // V^T staging (raw bf16)
  __shared__ float Kf[64 * 64];
  int c = blockIdx.x, g = blockIdx.y, b = blockIdx.z;
  int tid = threadIdx.x;
  int s0 = c * QB;
  {
    int j = tid >> 2, f0 = (tid & 3) * 16;
    const unsigned short* kr = &qkvb[(size_t)(b * S_ + s0 + j) * QKVW + 1024 + g * 64 + f0];
    const unsigned short* vr = &qkvb[(size_t)(b * S_ + s0 + j) * QKVW + 1280 + g * 64 + f0];
    uint4 k0_ = *(const uint4*)kr;
    uint4 k1_ = *(const uint4*)(kr + 8);
    const unsigned short* ks = (const unsigned short*)&k0_;
#pragma unroll
    for (int e = 0; e < 8; ++e) Kf[j * 64 + f0 + e] = b2f(ks[e]);
    ks = (const unsigned short*)&k1_;
#pragma unroll
    for (int e = 0; e < 8; ++e) Kf[j * 64 + f0 + 8 + e] = b2f(ks[e]);
    *(uint4*)&tl[j][f0] = *(const uint4*)vr;
    *(uint4*)&tl[j][f0 + 8] = *(const uint4*)(vr + 8);
  }
  __syncthreads();
  // write vt[b][g][d][s] bf16
  {
    int ty = tid >> 4, tx4 = (tid & 15) * 4;
#pragma unroll
    for (int rep = 0; rep < 4; ++rep) {
      int d = ty + rep * 16;
      ushort4 o;
      o.x = tl[tx4 + 0][d]; o.y = tl[tx4 + 1][d];
      o.z = tl[tx4 + 2][d]; o.w = tl[tx4 + 3][d];
      *(ushort4*)&vt[((size_t)(b * HKV_ + g) * 64 + d) * S_ + s0 + tx4] = o;
    }
  }
  // per-chunk sums St_c[d][f] and z_c[f]
  int d = tid >> 2, f0 = (tid & 3) * 16;
  float acc[16];
#pragma unroll
  for (int e = 0; e < 16; ++e) acc[e] = 0.f;
#pragma unroll 4
  for (int j = 0; j < QB; ++j) {
    float vv = b2f(tl[j][d]);
    const float* kfr = &Kf[j * 64 + f0];
#pragma unroll
    for (int e = 0; e < 16; ++e) acc[e] += vv * kfr[e];
  }
  size_t base = ((size_t)((b * HKV_ + g) * NC + c) * 65 + d) * 64 + f0;
#pragma unroll
  for (int e = 0; e < 16; ++e) stc[base + e] = acc[e];
  if (tid < 64) {
    float z = 0.f;
    for (int j = 0; j < QB; ++j) z += Kf[j * 64 + tid];
    stc[((size_t)((b * HKV_ + g) * NC + c) * 65 + 64) * 64 + tid] = z;
  }
}

// ------- exclusive prefix over chunks — one thread per element, TLP-hidden -------
__global__ __launch_bounds__(256) void k_scan(const float* __restrict__ stc,
                                              unsigned short* __restrict__ stp,
                                              float* __restrict__ zp) {
  int t = blockIdx.x * 256 + threadIdx.x;
  if (t >= 8 * 65 * 64) return;
  int bg = t / (65 * 64);
  int e = t - bg * (65 * 64);
  int d = e >> 6, f = e & 63;
  float run = 0.f;
#pragma unroll
  for (int c = 0; c < NC; ++c) {
    if (d < 64) stp[(size_t)(bg * NC + c) * 4096 + e] = f2b(run);
    else        zp[(bg * NC + c) * 64 + f] = run;
    run += stc[((size_t)(bg * NC + c) * 65 + d) * 64 + f];
  }
}

// ---------- per-(chunk, head-pair) attention; 2 heads share K/V/S/z loads ----------
// 512 threads: waves 0-3 -> head h0=hp*2, waves 4-7 -> head h1=hp*2+1.
// Output cols for the pair are contiguous (hp*128..+127) -> coalesced store via LDS.
__global__ __launch_bounds__(512) void k_attn(const unsigned short* __restrict__ qkvb,
                                              const unsigned short* __restrict__ vt,
                                              const unsigned short* __restrict__ stp,
                                              const float* __restrict__ zp,
                                              unsigned short* __restrict__ ob) {
  __shared__ __align__(16) unsigned short Qf[2][64 * 64];
  __shared__ __align__(16) unsigned short Kf[64 * 64];
  __shared__ __align__(16) unsigned short Vl[64 * 64];
  __shared__ __align__(16) unsigned short Sl[64 * 64];
  __shared__ __align__(16) unsigned short P[2][64 * 64];
  __shared__ __align__(16) unsigned short Ol[64][144];
  __shared__ float zl[64];
  __shared__ float den[2][64];
  int c = blockIdx.x, hp = blockIdx.y, b = blockIdx.z;
  int g = hp >> 1;
  int tid = threadIdx.x, lane = tid & 63, wave = tid >> 6;
  int s0 = c * QB;
  {
    int hsel = tid >> 8, t = tid & 255;
    int j = t >> 2, f0 = (t & 3) * 16;
    const unsigned short* qr =
        &qkvb[(size_t)(b * S_ + s0 + j) * QKVW + (hp * 2 + hsel) * 64 + f0];
    *(uint4*)&Qf[hsel][SW(j, j * 64 + f0)]     = *(const uint4*)qr;
    *(uint4*)&Qf[hsel][SW(j, j * 64 + f0 + 8)] = *(const uint4*)(qr + 8);
    if (tid < 256) {
      const unsigned short* kr =
          &qkvb[(size_t)(b * S_ + s0 + j) * QKVW + 1024 + g * 64 + f0];
      *(uint4*)&Kf[SW(j, j * 64 + f0)]     = *(const uint4*)kr;
      *(uint4*)&Kf[SW(j, j * 64 + f0 + 8)] = *(const uint4*)(kr + 8);
    } else {
      const unsigned short* vbase = &vt[((size_t)(b * HKV_ + g) * 64) * S_ + s0];
#pragma unroll
      for (int i2 = 0; i2 < 2; ++i2) {
        int cc = t * 2 + i2;
        int dd = cc >> 3, col = (cc & 7) * 8;
        *(uint4*)&Vl[SW(dd, cc * 8)] = *(const uint4*)&vbase[(size_t)dd * S_ + col];
      }
    }
    const unsigned short* sbase = &stp[(size_t)((b * HKV_ + g) * NC + c) * 4096];
    { int dd = tid >> 3; *(uint4*)&Sl[SW(dd, tid * 8)] = *(const uint4*)&sbase[tid * 8]; }
    if (tid < 64) zl[tid] = zp[((b * HKV_ + g) * NC + c) * 64 + tid];
  }
  __syncthreads();
  const int lr = lane & 15, lq = lane >> 4, lk = lq * 8;
  const int hh = wave >> 2, rw = (wave & 3) * 16;
  const f32x4 fzero = {0.f, 0.f, 0.f, 0.f};
  bf8 aQ[2];
#pragma unroll
  for (int kk = 0; kk < 2; ++kk)
    aQ[kk] = *(const bf8*)&Qf[hh][SW(rw + lr, (rw + lr) * 64 + kk * 32 + lk)];
  f32x4 sc[4];
#pragma unroll
  for (int nj = 0; nj < 4; ++nj) sc[nj] = fzero;
#pragma unroll
  for (int nj = 0; nj < 4; ++nj)
#pragma unroll
    for (int kk = 0; kk < 2; ++kk) {
      bf8 bk8 = *(const bf8*)&Kf[SW(nj * 16 + lr, (nj * 16 + lr) * 64 + kk * 32 + lk)];
      sc[nj] = MFMA_B16(aQ[kk], bk8, sc[nj]);
    }
  // causal mask (diag included) + store P as bf16
#pragma unroll
  for (int nj = 0; nj < 4; ++nj)
#pragma unroll
    for (int r = 0; r < 4; ++r) {
      int i = rw + lq * 4 + r;
      int j = nj * 16 + lr;
      float v = (j <= i) ? sc[nj][r] : 0.f;
      P[hh][SW(i, i * 64 + j)] = f2b(v);
    }
  __syncthreads();
  // den[hd][i] = rowsum(P[hd][i]) + Qf[hd][i] . z_prev
  {
    int hd = tid >> 8, t = tid & 255;
    int i = t >> 2, q = t & 3, f0 = q * 16;
    float s = 0.f;
#pragma unroll
    for (int e = 0; e < 16; ++e) s += b2f(P[hd][SW(i, i * 64 + f0 + e)]);
#pragma unroll
    for (int e = 0; e < 16; ++e) s += b2f(Qf[hd][SW(i, i * 64 + f0 + e)]) * zl[f0 + e];
    s += __shfl_xor(s, 1);
    s += __shfl_xor(s, 2);
    if (q == 0) den[hd][i] = s;
  }
  // O = P @ V + Qf @ S_prev
  f32x4 oa[4];
#pragma unroll
  for (int nd = 0; nd < 4; ++nd) oa[nd] = fzero;
  bf8 aP[2];
#pragma unroll
  for (int kk = 0; kk < 2; ++kk)
    aP[kk] = *(const bf8*)&P[hh][SW(rw + lr, (rw + lr) * 64 + kk * 32 + lk)];
#pragma unroll
  for (int nd = 0; nd < 4; ++nd)
#pragma unroll
    for (int kk = 0; kk < 2; ++kk) {
      bf8 bS = *(const bf8*)&Sl[SW(nd * 16 + lr, (nd * 16 + lr) * 64 + kk * 32 + lk)];
      oa[nd] = MFMA_B16(aQ[kk], bS, oa[nd]);
      bf8 bV = *(const bf8*)&Vl[SW(nd * 16 + lr, (nd * 16 + lr) * 64 + kk * 32 + lk)];
      oa[nd] = MFMA_B16(aP[kk], bV, oa[nd]);
    }
  __syncthreads();   // den visible; P/K/V reads done
#pragma unroll
  for (int nd = 0; nd < 4; ++nd)
#pragma unroll
    for (int r = 0; r < 4; ++r) {
      int i = rw + lq * 4 + r;
      int dd = nd * 16 + lr;
      Ol[i][hh * 64 + dd] = f2b(oa[nd][r] / (den[hh][i] + 1e-6f));
    }
  __syncthreads();
  // coalesced store: 64 rows x 128 cols (heads h0|h1 adjacent)
  {
    int j = tid >> 3, u = tid & 7;
    unsigned short* orow = &ob[(size_t)(b * S_ + s0 + j) * D_ + hp * 128 + u * 16];
    *(uint4*)orow       = *(const uint4*)&Ol[j][u * 16];
    *(uint4*)(orow + 8) = *(const uint4*)&Ol[j][u * 16 + 8];
  }
}

// ------- residual + LayerNorm -------
__global__ __launch_bounds__(256) void k_ln(const float* __restrict__ x,
                                            const float* __restrict__ o2,
                                            const float* __restrict__ gamma,
                                            const float* __restrict__ beta,
                                            float* __restrict__ out) {
  int row = blockIdx.x, tid = threadIdx.x;
  float4 xv = ((const float4*)(x + (size_t)row * D_))[tid];
  float4 ov = ((const float4*)(o2 + (size_t)row * D_))[tid];
  float4 y;
  y.x = xv.x + ov.x; y.y = xv.y + ov.y; y.z = xv.z + ov.z; y.w = xv.w + ov.w;
  float s = y.x + y.y + y.z + y.w;
  float ss = y.x * y.x + y.y * y.y + y.z * y.z + y.w * y.w;
#pragma unroll
  for (int off = 32; off > 0; off >>= 1) {
    s += __shfl_down(s, off);
    ss += __shfl_down(ss, off);
  }
  __shared__ float red[8];
  int lane = tid & 63, wave = tid >> 6;
  if (lane == 0) { red[wave] = s; red[4 + wave] = ss; }
  __syncthreads();
  if (tid == 0) {
    red[0] = red[0] + red[1] + red[2] + red[3];
    red[4] = red[4] + red[5] + red[6] + red[7];
  }
  __syncthreads();
  float mu = red[0] * (1.f / D_);
  float var = red[4] * (1.f / D_) - mu * mu;
  float rs = rsqrtf(var + 1e-5f);
  float4 g4 = ((const float4*)gamma)[tid];
  float4 b4 = ((const float4*)beta)[tid];
  float4 o;
  o.x = (y.x - mu) * rs * g4.x + b4.x;
  o.y = (y.y - mu) * rs * g4.y + b4.y;
  o.z = (y.z - mu) * rs * g4.z + b4.z;
  o.w = (y.w - mu) * rs * g4.w + b4.w;
  ((float4*)(out + (size_t)row * D_))[tid] = o;
}

extern "C" void kernel_launch(void* const* d_in, const int* in_sizes, int n_in,
                              void* d_out, int out_size, void* d_ws, size_t ws_size,
                              hipStream_t stream) {
  const float* x     = (const float*)d_in[0];
  const float* Wq    = (const float*)d_in[1];
  const float* bq    = (const float*)d_in[2];
  const float* Wk    = (const float*)d_in[3];
  const float* bk    = (const float*)d_in[4];
  const float* Wv    = (const float*)d_in[5];
  const float* bv    = (const float*)d_in[6];
  const float* Wc    = (const float*)d_in[7];
  const float* We    = (const float*)d_in[8];
  const float* Wo    = (const float*)d_in[9];
  const float* bo    = (const float*)d_in[10];
  const float* gamma = (const float*)d_in[11];
  const float* beta  = (const float*)d_in[12];

  char* p = (char*)d_ws;
  size_t off = 0;
  auto carve = [&](size_t bytes) {
    void* r = p + off;
    off = (off + bytes + 255) & ~(size_t)255;
    return r;
  };
  unsigned short* xb     = (unsigned short*)carve((size_t)BS_ * D_ * 2);
  unsigned short* Wqkv_t = (unsigned short*)carve((size_t)QKVW * D_ * 2);
  unsigned short* Wo_t   = (unsigned short*)carve((size_t)D_ * D_ * 2);
  float*          biasq  = (float*)carve(QKVW * 4);
  unsigned short* qkvb   = (unsigned short*)carve((size_t)BS_ * QKVW * 2);
  unsigned short* Wc_b   = (unsigned short*)carve(256 * 64 * 2);
  unsigned short* We_t   = (unsigned short*)carve(256 * 64 * 2);
  float*          Wce    = (float*)carve(256 * 256 * 4);
  unsigned short* Wce_t  = (unsigned short*)carve(256 * 256 * 2);
  unsigned short* Wkv_b  = (unsigned short*)carve((size_t)2048 * 256 * 2);
  unsigned short* vtb    = (unsigned short*)carve((size_t)8 * 64 * S_ * 2);
  float*          stc    = (float*)carve((size_t)8 * NC * 65 * 64 * 4);
  unsigned short* stp    = (unsigned short*)carve((size_t)8 * NC * 4096 * 2);
  float*          zp     = (float*)carve((size_t)8 * NC * 64 * 4);
  unsigned short* obuf   = (unsigned short*)carve((size_t)BS_ * D_ * 2);
  float*          o2     = (float*)carve((size_t)BS_ * D_ * 4);

  // P1: all independent prep (x conv, Wk/Wv conv, Wq/Wo transpose, Wc/We prep)
  k_prep<<<3092, 256, 0, stream>>>(x, Wq, Wo, Wk, Wv, Wc, We,
                                   xb, Wqkv_t, Wo_t, Wkv_b, Wc_b, We_t);
  // P2: T = Wc @ We -> Wce (f32) + Wce_t (bf16, transposed)  [M=256,N=256,K=64]
  k_gemm<3><<<dim3(2, 4), 128, 0, stream>>>(Wc_b, We_t, nullptr, Wce, Wce_t,
                                            256, 64, nullptr, nullptr, nullptr, nullptr);
  // P3: folded K/V weights into Wqkv_t rows [1024,1536) + bias fold (y==4)
  k_gemm<2><<<dim3(16, 5), 128, 0, stream>>>(Wce_t, Wkv_b, nullptr, Wqkv_t, biasq,
                                             2048, 256, bq, bk, bv, Wce);
  // P4: fused QKV projection -> qkvb bf16 (Q,K pre-featted) [M=2048,N=1536,K=1024]
  k_gemm<1><<<dim3(12, 32), 128, 0, stream>>>(xb, Wqkv_t, biasq, qkvb, nullptr,
                                              QKVW, 1024, nullptr, nullptr, nullptr, nullptr);
  // P5: V transpose + per-chunk KV sums
  k_vkv<<<dim3(NC, HKV_, B_), 256, 0, stream>>>(qkvb, vtb, stc);
  // P5b: parallel exclusive chunk-prefix
  k_scan<<<(8 * 65 * 64 + 255) / 256, 256, 0, stream>>>(stc, stp, zp);
  // P6: attention, 2 heads per block
  k_attn<<<dim3(NC, H_ / 2, B_), 512, 0, stream>>>(qkvb, vtb, stp, zp, obuf);
  // P7: output projection [M=2048,N=1024,K=1024]
  k_gemm<0><<<dim3(8, 32), 128, 0, stream>>>(obuf, Wo_t, bo, o2, nullptr,
                                             1024, 1024, nullptr, nullptr, nullptr, nullptr);
  // P8: residual + LayerNorm
  k_ln<<<BS_, 256, 0, stream>>>(x, o2, gamma, beta, (float*)d_out);
}

// Round 7
// 97.502 us; speedup vs baseline: 1.0621x; 1.0621x over previous
//
#include <hip/hip_runtime.h>

#define D_ 1024
#define H_ 16
#define HKV_ 4
#define B_ 2
#define S_ 1024
#define BS_ (B_*S_)
#define QKVW 1536
#define QB 64
#define NC (S_/QB)

typedef short bf8 __attribute__((ext_vector_type(8)));
typedef float f32x4 __attribute__((ext_vector_type(4)));

#define MFMA_B16(a,b,c) __builtin_amdgcn_mfma_f32_16x16x32_bf16((a),(b),(c),0,0,0)

// async global->LDS, 16B per lane; LDS dest must be linear in lane order
#define GLOAD16(g, l) __builtin_amdgcn_global_load_lds( \
    (const __attribute__((address_space(1))) void*)(g), \
    (__attribute__((address_space(3))) void*)(l), 16, 0, 0)

// LDS XOR swizzle for [64][64] bf16 tiles: flips 16B-unit within 8-row stripe.
#define SW(row, idx) ((idx) ^ (((row) & 7) << 3))

__device__ __forceinline__ unsigned short f2b(float f) {
  unsigned int u = __float_as_uint(f);
  u += 0x7FFFu + ((u >> 16) & 1u);
  return (unsigned short)(u >> 16);
}
__device__ __forceinline__ float b2f(unsigned short h) {
  return __uint_as_float(((unsigned int)h) << 16);
}
__device__ __forceinline__ float feat(float x) { return x > 0.f ? x + 1.f : __expf(x); }

// ---------- helpers used by the fused prep kernel ----------
__device__ __forceinline__ void conv_body(const float* __restrict__ src,
                                          unsigned short* __restrict__ dst,
                                          int sub, int n4, int tid) {
  int i = sub * 256 + tid;
  if (i >= n4) return;
  float4 v = ((const float4*)src)[i];
  ushort4 o;
  o.x = f2b(v.x); o.y = f2b(v.y); o.z = f2b(v.z); o.w = f2b(v.w);
  ((ushort4*)dst)[i] = o;
}

__device__ __forceinline__ void tconv_body(const float* __restrict__ src,
                                           unsigned short* __restrict__ dst,
                                           int bx, int by, int ss, int ds,
                                           int tid, float (*tl)[65]) {
  int r0 = by * 64, c0 = bx * 64;
  int ty = tid >> 4, tx4 = (tid & 15) * 4;
#pragma unroll
  for (int rep = 0; rep < 4; ++rep) {
    int r = ty + rep * 16;
    float4 v = *(const float4*)&src[(size_t)(r0 + r) * ss + c0 + tx4];
    tl[r][tx4] = v.x; tl[r][tx4 + 1] = v.y; tl[r][tx4 + 2] = v.z; tl[r][tx4 + 3] = v.w;
  }
  __syncthreads();
#pragma unroll
  for (int rep = 0; rep < 4; ++rep) {
    int c = ty + rep * 16;
    ushort4 o;
    o.x = f2b(tl[tx4 + 0][c]); o.y = f2b(tl[tx4 + 1][c]);
    o.z = f2b(tl[tx4 + 2][c]); o.w = f2b(tl[tx4 + 3][c]);
    *(ushort4*)&dst[(size_t)(c0 + c) * ds + r0 + tx4] = o;
  }
}

// ---------- P1: all independent elementwise/transpose prep in one kernel ----------
__global__ __launch_bounds__(256) void k_prep(const float* __restrict__ x,
                                              const float* __restrict__ Wq,
                                              const float* __restrict__ Wo,
                                              const float* __restrict__ Wk,
                                              const float* __restrict__ Wv,
                                              const float* __restrict__ Wc,
                                              const float* __restrict__ We,
                                              unsigned short* __restrict__ xb,
                                              unsigned short* __restrict__ Wqkv_t,
                                              unsigned short* __restrict__ Wo_t,
                                              unsigned short* __restrict__ Wkv_b,
                                              unsigned short* __restrict__ Wc_b,
                                              unsigned short* __restrict__ We_t) {
  __shared__ float tl[64][65];
  int blk = blockIdx.x, tid = threadIdx.x;
  if (blk < 2048) {
    conv_body(x, xb, blk, BS_ * D_ / 4, tid);
  } else if (blk < 2304) {
    conv_body(Wk, Wkv_b, blk - 2048, 1024 * 256 / 4, tid);
  } else if (blk < 2560) {
    conv_body(Wv, Wkv_b + 1024 * 256, blk - 2304, 1024 * 256 / 4, tid);
  } else if (blk < 2816) {
    int sb = blk - 2560;
    tconv_body(Wq, Wqkv_t, sb & 15, sb >> 4, 1024, 1024, tid, tl);
  } else if (blk < 3072) {
    int sb = blk - 2816;
    tconv_body(Wo, Wo_t, sb & 15, sb >> 4, 1024, 1024, tid, tl);
  } else if (blk < 3088) {
    conv_body(Wc, Wc_b, blk - 3072, 256 * 64 / 4, tid);
  } else {
    tconv_body(We, We_t, blk - 3088, 0, 256, 64, tid, tl);
  }
}

// ---------- 1-wave 64x64 bt-GEMM: no barriers, dbuf LDS, counted vmcnt ----------
// MODE 0: f32 out + bias (O-proj);  MODE 1: bf16 out + bias + feat col<1280 (QKV)
// LDS tiles [64][32] shorts; 16B-chunk index XOR-swizzled with (row&3) on BOTH
// the global_load_lds source address and the ds_read (rule: both-sides-or-neither).
template<int MODE>
__global__ __launch_bounds__(64) void k_gemm1(const unsigned short* __restrict__ A,
                                              const unsigned short* __restrict__ Bt,
                                              const float* __restrict__ bias,
                                              void* __restrict__ C,
                                              int N, int K) {
  __shared__ __align__(16) unsigned short As[2][64 * 32];
  __shared__ __align__(16) unsigned short Bs[2][64 * 32];
  const int lane = threadIdx.x;
  const int row0 = blockIdx.y * 64, col0 = blockIdx.x * 64;
  const int lr = lane & 15, lq = lane >> 4;
  const int sr = lane >> 2, sj = lane & 3;    // staging: row-in-16-group, chunk
  const f32x4 fzero = {0.f, 0.f, 0.f, 0.f};
  f32x4 acc[4][4];
#pragma unroll
  for (int i = 0; i < 4; ++i)
#pragma unroll
    for (int j = 0; j < 4; ++j) acc[i][j] = fzero;

#define STAGE1(pb, k0)                                                          \
  {                                                                             \
    _Pragma("unroll")                                                           \
    for (int i = 0; i < 4; ++i) {                                               \
      int r = i * 16 + sr;                                                      \
      int js = sj ^ (r & 3);                                                    \
      GLOAD16(&A[(size_t)(row0 + r) * K + (k0) + js * 8],                       \
              &As[pb][(i * 64 + lane) * 8]);                                    \
    }                                                                           \
    _Pragma("unroll")                                                           \
    for (int i = 0; i < 4; ++i) {                                               \
      int r = i * 16 + sr;                                                      \
      int js = sj ^ (r & 3);                                                    \
      GLOAD16(&Bt[(size_t)(col0 + r) * K + (k0) + js * 8],                      \
              &Bs[pb][(i * 64 + lane) * 8]);                                    \
    }                                                                           \
  }

  STAGE1(0, 0);
  int cur = 0;
  for (int k0 = 0; k0 < K; k0 += 32) {
    if (k0 + 32 < K) {
      STAGE1(cur ^ 1, k0 + 32);
      asm volatile("s_waitcnt vmcnt(8)" ::: "memory");   // drain current buffer only
    } else {
      asm volatile("s_waitcnt vmcnt(0)" ::: "memory");
    }
    __builtin_amdgcn_sched_barrier(0);
    bf8 af[4], bfr[4];
#pragma unroll
    for (int mi = 0; mi < 4; ++mi) {
      int ra = mi * 16 + lr;
      af[mi] = *(const bf8*)&As[cur][ra * 32 + ((lq ^ (ra & 3)) * 8)];
    }
#pragma unroll
    for (int ni = 0; ni < 4; ++ni) {
      int rb = ni * 16 + lr;
      bfr[ni] = *(const bf8*)&Bs[cur][rb * 32 + ((lq ^ (rb & 3)) * 8)];
    }
#pragma unroll
    for (int mi = 0; mi < 4; ++mi)
#pragma unroll
      for (int ni = 0; ni < 4; ++ni)
        acc[mi][ni] = MFMA_B16(af[mi], bfr[ni], acc[mi][ni]);
    cur ^= 1;
  }
#undef STAGE1
#pragma unroll
  for (int ni = 0; ni < 4; ++ni) {
    int col = col0 + ni * 16 + lr;
    float bv = bias[col];
#pragma unroll
    for (int mi = 0; mi < 4; ++mi)
#pragma unroll
      for (int r = 0; r < 4; ++r) {
        int row = row0 + mi * 16 + lq * 4 + r;
        float v = acc[mi][ni][r] + bv;
        if (MODE == 1) {
          if (col < 1280) v = feat(v);
          ((unsigned short*)C)[(size_t)row * N + col] = f2b(v);
        } else {
          ((float*)C)[(size_t)row * N + col] = v;
        }
      }
  }
}

// ---------- small bt-GEMM (weight prep only), 64x128 tile, 2 waves ----------
// MODE 2: foldKV bf16 remap out; blockIdx.y==4 -> fused bias fold
// MODE 3: T-both: f32 C + bf16 transposed C2
template<int MODE>
__global__ __launch_bounds__(128) void k_gemm(const unsigned short* __restrict__ A,
                                              const unsigned short* __restrict__ Bt,
                                              void* __restrict__ C,
                                              void* __restrict__ C2,
                                              int N, int K,
                                              const float* __restrict__ fbq,
                                              const float* __restrict__ fbk,
                                              const float* __restrict__ fbv,
                                              const float* __restrict__ fWce) {
  if (MODE == 2 && blockIdx.y == 4) {
    // fused qkv bias: [bq | bk@Wce | bv@Wce]
    int t = blockIdx.x * 128 + threadIdx.x;
    if (t >= QKVW) return;
    float* biasq = (float*)C2;
    if (t < 1024) { biasq[t] = fbq[t]; return; }
    const float* b = (t < 1280) ? fbk : fbv;
    int n = (t < 1280) ? (t - 1024) : (t - 1280);
    float s = 0.f;
    for (int j = 0; j < 256; ++j) s += b[j] * fWce[j * 256 + n];
    biasq[t] = s;
    return;
  }
  __shared__ __align__(16) unsigned short As[64 * 32];
  __shared__ __align__(16) unsigned short Bs[128 * 32];
  const int tid = threadIdx.x;
  const int lane = tid & 63, wave = tid >> 6;
  const int row0 = blockIdx.y * 64, col0 = blockIdx.x * 128;
  const f32x4 fzero = {0.f, 0.f, 0.f, 0.f};
  f32x4 acc[4][4];
#pragma unroll
  for (int i = 0; i < 4; ++i)
#pragma unroll
    for (int j = 0; j < 4; ++j) acc[i][j] = fzero;
  const int lr = lane & 15, lq = lane >> 4, lk = lq * 8;
  for (int k0 = 0; k0 < K; k0 += 32) {
#pragma unroll
    for (int i = 0; i < 2; ++i) {
      int e = (tid + i * 128) * 8;
      int r = e >> 5, c = e & 31;
      GLOAD16(&A[(size_t)(row0 + r) * K + k0 + c], &As[e]);
    }
#pragma unroll
    for (int i = 0; i < 4; ++i) {
      int e = (tid + i * 128) * 8;
      int r = e >> 5, c = e & 31;
      GLOAD16(&Bt[(size_t)(col0 + r) * K + k0 + c], &Bs[e]);
    }
    __syncthreads();
    bf8 af[4], bfr[4];
#pragma unroll
    for (int mi = 0; mi < 4; ++mi)
      af[mi] = *(const bf8*)&As[(mi * 16 + lr) * 32 + lk];
#pragma unroll
    for (int ni = 0; ni < 4; ++ni)
      bfr[ni] = *(const bf8*)&Bs[(wave * 64 + ni * 16 + lr) * 32 + lk];
#pragma unroll
    for (int mi = 0; mi < 4; ++mi)
#pragma unroll
      for (int ni = 0; ni < 4; ++ni)
        acc[mi][ni] = MFMA_B16(af[mi], bfr[ni], acc[mi][ni]);
    __syncthreads();
  }
#pragma unroll
  for (int mi = 0; mi < 4; ++mi)
#pragma unroll
    for (int ni = 0; ni < 4; ++ni) {
      int col = col0 + wave * 64 + ni * 16 + lr;
#pragma unroll
      for (int r = 0; r < 4; ++r) {
        int row = row0 + mi * 16 + lq * 4 + r;
        float v = acc[mi][ni][r];
        if (MODE == 2) {
          int sec = col >> 10, cc = col & 1023;
          ((unsigned short*)C)[(size_t)(1024 + sec * 256 + row) * 1024 + cc] = f2b(v);
        } else {  // MODE 3
          ((float*)C)[(size_t)row * 256 + col] = v;
          ((unsigned short*)C2)[(size_t)col * 256 + row] = f2b(v);
        }
      }
    }
}

// ---------- fused V-transpose + per-chunk KV sums (qkvb bf16, K pre-featted) ----------
__global__ __launch_bounds__(256) void k_vkv(const unsigned short* __restrict__ qkvb,
                                             unsigned short* __restrict__ vt,
                                             float* __restrict__ stc) {
  __shared__ unsigned short tl[64][72];   // V^T staging (raw bf16)
  __shared__ float Kf[64 * 64];
  int c = blockIdx.x, g = blockIdx.y, b = blockIdx.z;
  int tid = threadIdx.x;
  int s0 = c * QB;
  {
    int j = tid >> 2, f0 = (tid & 3) * 16;
    const unsigned short* kr = &qkvb[(size_t)(b * S_ + s0 + j) * QKVW + 1024 + g * 64 + f0];
    const unsigned short* vr = &qkvb[(size_t)(b * S_ + s0 + j) * QKVW + 1280 + g * 64 + f0];
    uint4 k0_ = *(const uint4*)kr;
    uint4 k1_ = *(const uint4*)(kr + 8);
    const unsigned short* ks = (const unsigned short*)&k0_;
#pragma unroll
    for (int e = 0; e < 8; ++e) Kf[j * 64 + f0 + e] = b2f(ks[e]);
    ks = (const unsigned short*)&k1_;
#pragma unroll
    for (int e = 0; e < 8; ++e) Kf[j * 64 + f0 + 8 + e] = b2f(ks[e]);
    *(uint4*)&tl[j][f0] = *(const uint4*)vr;
    *(uint4*)&tl[j][f0 + 8] = *(const uint4*)(vr + 8);
  }
  __syncthreads();
  // write vt[b][g][d][s] bf16
  {
    int ty = tid >> 4, tx4 = (tid & 15) * 4;
#pragma unroll
    for (int rep = 0; rep < 4; ++rep) {
      int d = ty + rep * 16;
      ushort4 o;
      o.x = tl[tx4 + 0][d]; o.y = tl[tx4 + 1][d];
      o.z = tl[tx4 + 2][d]; o.w = tl[tx4 + 3][d];
      *(ushort4*)&vt[((size_t)(b * HKV_ + g) * 64 + d) * S_ + s0 + tx4] = o;
    }
  }
  // per-chunk sums St_c[d][f] and z_c[f]
  int d = tid >> 2, f0 = (tid & 3) * 16;
  float acc[16];
#pragma unroll
  for (int e = 0; e < 16; ++e) acc[e] = 0.f;
#pragma unroll 4
  for (int j = 0; j < QB; ++j) {
    float vv = b2f(tl[j][d]);
    const float* kfr = &Kf[j * 64 + f0];
#pragma unroll
    for (int e = 0; e < 16; ++e) acc[e] += vv * kfr[e];
  }
  size_t base = ((size_t)((b * HKV_ + g) * NC + c) * 65 + d) * 64 + f0;
#pragma unroll
  for (int e = 0; e < 16; ++e) stc[base + e] = acc[e];
  if (tid < 64) {
    float z = 0.f;
    for (int j = 0; j < QB; ++j) z += Kf[j * 64 + tid];
    stc[((size_t)((b * HKV_ + g) * NC + c) * 65 + 64) * 64 + tid] = z;
  }
}

// ------- exclusive prefix over chunks — one thread per element, TLP-hidden -------
__global__ __launch_bounds__(256) void k_scan(const float* __restrict__ stc,
                                              unsigned short* __restrict__ stp,
                                              float* __restrict__ zp) {
  int t = blockIdx.x * 256 + threadIdx.x;
  if (t >= 8 * 65 * 64) return;
  int bg = t / (65 * 64);
  int e = t - bg * (65 * 64);
  int d = e >> 6, f = e & 63;
  float run = 0.f;
#pragma unroll
  for (int c = 0; c < NC; ++c) {
    if (d < 64) stp[(size_t)(bg * NC + c) * 4096 + e] = f2b(run);
    else        zp[(bg * NC + c) * 64 + f] = run;
    run += stc[((size_t)(bg * NC + c) * 65 + d) * 64 + f];
  }
}

// ---------- per-(chunk, head-pair) attention; 2 heads share K/V/S/z loads ----------
__global__ __launch_bounds__(512) void k_attn(const unsigned short* __restrict__ qkvb,
                                              const unsigned short* __restrict__ vt,
                                              const unsigned short* __restrict__ stp,
                                              const float* __restrict__ zp,
                                              unsigned short* __restrict__ ob) {
  __shared__ __align__(16) unsigned short Qf[2][64 * 64];
  __shared__ __align__(16) unsigned short Kf[64 * 64];
  __shared__ __align__(16) unsigned short Vl[64 * 64];
  __shared__ __align__(16) unsigned short Sl[64 * 64];
  __shared__ __align__(16) unsigned short P[2][64 * 64];
  __shared__ __align__(16) unsigned short Ol[64][144];
  __shared__ float zl[64];
  __shared__ float den[2][64];
  int c = blockIdx.x, hp = blockIdx.y, b = blockIdx.z;
  int g = hp >> 1;
  int tid = threadIdx.x, lane = tid & 63, wave = tid >> 6;
  int s0 = c * QB;
  {
    int hsel = tid >> 8, t = tid & 255;
    int j = t >> 2, f0 = (t & 3) * 16;
    const unsigned short* qr =
        &qkvb[(size_t)(b * S_ + s0 + j) * QKVW + (hp * 2 + hsel) * 64 + f0];
    *(uint4*)&Qf[hsel][SW(j, j * 64 + f0)]     = *(const uint4*)qr;
    *(uint4*)&Qf[hsel][SW(j, j * 64 + f0 + 8)] = *(const uint4*)(qr + 8);
    if (tid < 256) {
      const unsigned short* kr =
          &qkvb[(size_t)(b * S_ + s0 + j) * QKVW + 1024 + g * 64 + f0];
      *(uint4*)&Kf[SW(j, j * 64 + f0)]     = *(const uint4*)kr;
      *(uint4*)&Kf[SW(j, j * 64 + f0 + 8)] = *(const uint4*)(kr + 8);
    } else {
      const unsigned short* vbase = &vt[((size_t)(b * HKV_ + g) * 64) * S_ + s0];
#pragma unroll
      for (int i2 = 0; i2 < 2; ++i2) {
        int cc = t * 2 + i2;
        int dd = cc >> 3, col = (cc & 7) * 8;
        *(uint4*)&Vl[SW(dd, cc * 8)] = *(const uint4*)&vbase[(size_t)dd * S_ + col];
      }
    }
    const unsigned short* sbase = &stp[(size_t)((b * HKV_ + g) * NC + c) * 4096];
    { int dd = tid >> 3; *(uint4*)&Sl[SW(dd, tid * 8)] = *(const uint4*)&sbase[tid * 8]; }
    if (tid < 64) zl[tid] = zp[((b * HKV_ + g) * NC + c) * 64 + tid];
  }
  __syncthreads();
  const int lr = lane & 15, lq = lane >> 4, lk = lq * 8;
  const int hh = wave >> 2, rw = (wave & 3) * 16;
  const f32x4 fzero = {0.f, 0.f, 0.f, 0.f};
  bf8 aQ[2];
#pragma unroll
  for (int kk = 0; kk < 2; ++kk)
    aQ[kk] = *(const bf8*)&Qf[hh][SW(rw + lr, (rw + lr) * 64 + kk * 32 + lk)];
  f32x4 sc[4];
#pragma unroll
  for (int nj = 0; nj < 4; ++nj) sc[nj] = fzero;
#pragma unroll
  for (int nj = 0; nj < 4; ++nj)
#pragma unroll
    for (int kk = 0; kk < 2; ++kk) {
      bf8 bk8 = *(const bf8*)&Kf[SW(nj * 16 + lr, (nj * 16 + lr) * 64 + kk * 32 + lk)];
      sc[nj] = MFMA_B16(aQ[kk], bk8, sc[nj]);
    }
  // causal mask (diag included) + store P as bf16
#pragma unroll
  for (int nj = 0; nj < 4; ++nj)
#pragma unroll
    for (int r = 0; r < 4; ++r) {
      int i = rw + lq * 4 + r;
      int j = nj * 16 + lr;
      float v = (j <= i) ? sc[nj][r] : 0.f;
      P[hh][SW(i, i * 64 + j)] = f2b(v);
    }
  __syncthreads();
  // den[hd][i] = rowsum(P[hd][i]) + Qf[hd][i] . z_prev
  {
    int hd = tid >> 8, t = tid & 255;
    int i = t >> 2, q = t & 3, f0 = q * 16;
    float s = 0.f;
#pragma unroll
    for (int e = 0; e < 16; ++e) s += b2f(P[hd][SW(i, i * 64 + f0 + e)]);
#pragma unroll
    for (int e = 0; e < 16; ++e) s += b2f(Qf[hd][SW(i, i * 64 + f0 + e)]) * zl[f0 + e];
    s += __shfl_xor(s, 1);
    s += __shfl_xor(s, 2);
    if (q == 0) den[hd][i] = s;
  }
  // O = P @ V + Qf @ S_prev
  f32x4 oa[4];
#pragma unroll
  for (int nd = 0; nd < 4; ++nd) oa[nd] = fzero;
  bf8 aP[2];
#pragma unroll
  for (int kk = 0; kk < 2; ++kk)
    aP[kk] = *(const bf8*)&P[hh][SW(rw + lr, (rw + lr) * 64 + kk * 32 + lk)];
#pragma unroll
  for (int nd = 0; nd < 4; ++nd)
#pragma unroll
    for (int kk = 0; kk < 2; ++kk) {
      bf8 bS = *(const bf8*)&Sl[SW(nd * 16 + lr, (nd * 16 + lr) * 64 + kk * 32 + lk)];
      oa[nd] = MFMA_B16(aQ[kk], bS, oa[nd]);
      bf8 bV = *(const bf8*)&Vl[SW(nd * 16 + lr, (nd * 16 + lr) * 64 + kk * 32 + lk)];
      oa[nd] = MFMA_B16(aP[kk], bV, oa[nd]);
    }
  __syncthreads();   // den visible; P/K/V reads done
#pragma unroll
  for (int nd = 0; nd < 4; ++nd)
#pragma unroll
    for (int r = 0; r < 4; ++r) {
      int i = rw + lq * 4 + r;
      int dd = nd * 16 + lr;
      Ol[i][hh * 64 + dd] = f2b(oa[nd][r] / (den[hh][i] + 1e-6f));
    }
  __syncthreads();
  // coalesced store: 64 rows x 128 cols (heads h0|h1 adjacent)
  {
    int j = tid >> 3, u = tid & 7;
    unsigned short* orow = &ob[(size_t)(b * S_ + s0 + j) * D_ + hp * 128 + u * 16];
    *(uint4*)orow       = *(const uint4*)&Ol[j][u * 16];
    *(uint4*)(orow + 8) = *(const uint4*)&Ol[j][u * 16 + 8];
  }
}

// ------- residual + LayerNorm -------
__global__ __launch_bounds__(256) void k_ln(const float* __restrict__ x,
                                            const float* __restrict__ o2,
                                            const float* __restrict__ gamma,
                                            const float* __restrict__ beta,
                                            float* __restrict__ out) {
  int row = blockIdx.x, tid = threadIdx.x;
  float4 xv = ((const float4*)(x + (size_t)row * D_))[tid];
  float4 ov = ((const float4*)(o2 + (size_t)row * D_))[tid];
  float4 y;
  y.x = xv.x + ov.x; y.y = xv.y + ov.y; y.z = xv.z + ov.z; y.w = xv.w + ov.w;
  float s = y.x + y.y + y.z + y.w;
  float ss = y.x * y.x + y.y * y.y + y.z * y.z + y.w * y.w;
#pragma unroll
  for (int off = 32; off > 0; off >>= 1) {
    s += __shfl_down(s, off);
    ss += __shfl_down(ss, off);
  }
  __shared__ float red[8];
  int lane = tid & 63, wave = tid >> 6;
  if (lane == 0) { red[wave] = s; red[4 + wave] = ss; }
  __syncthreads();
  if (tid == 0) {
    red[0] = red[0] + red[1] + red[2] + red[3];
    red[4] = red[4] + red[5] + red[6] + red[7];
  }
  __syncthreads();
  float mu = red[0] * (1.f / D_);
  float var = red[4] * (1.f / D_) - mu * mu;
  float rs = rsqrtf(var + 1e-5f);
  float4 g4 = ((const float4*)gamma)[tid];
  float4 b4 = ((const float4*)beta)[tid];
  float4 o;
  o.x = (y.x - mu) * rs * g4.x + b4.x;
  o.y = (y.y - mu) * rs * g4.y + b4.y;
  o.z = (y.z - mu) * rs * g4.z + b4.z;
  o.w = (y.w - mu) * rs * g4.w + b4.w;
  ((float4*)(out + (size_t)row * D_))[tid] = o;
}

extern "C" void kernel_launch(void* const* d_in, const int* in_sizes, int n_in,
                              void* d_out, int out_size, void* d_ws, size_t ws_size,
                              hipStream_t stream) {
  const float* x     = (const float*)d_in[0];
  const float* Wq    = (const float*)d_in[1];
  const float* bq    = (const float*)d_in[2];
  const float* Wk    = (const float*)d_in[3];
  const float* bk    = (const float*)d_in[4];
  const float* Wv    = (const float*)d_in[5];
  const float* bv    = (const float*)d_in[6];
  const float* Wc    = (const float*)d_in[7];
  const float* We    = (const float*)d_in[8];
  const float* Wo    = (const float*)d_in[9];
  const float* bo    = (const float*)d_in[10];
  const float* gamma = (const float*)d_in[11];
  const float* beta  = (const float*)d_in[12];

  char* p = (char*)d_ws;
  size_t off = 0;
  auto carve = [&](size_t bytes) {
    void* r = p + off;
    off = (off + bytes + 255) & ~(size_t)255;
    return r;
  };
  unsigned short* xb     = (unsigned short*)carve((size_t)BS_ * D_ * 2);
  unsigned short* Wqkv_t = (unsigned short*)carve((size_t)QKVW * D_ * 2);
  unsigned short* Wo_t   = (unsigned short*)carve((size_t)D_ * D_ * 2);
  float*          biasq  = (float*)carve(QKVW * 4);
  unsigned short* qkvb   = (unsigned short*)carve((size_t)BS_ * QKVW * 2);
  unsigned short* Wc_b   = (unsigned short*)carve(256 * 64 * 2);
  unsigned short* We_t   = (unsigned short*)carve(256 * 64 * 2);
  float*          Wce    = (float*)carve(256 * 256 * 4);
  unsigned short* Wce_t  = (unsigned short*)carve(256 * 256 * 2);
  unsigned short* Wkv_b  = (unsigned short*)carve((size_t)2048 * 256 * 2);
  unsigned short* vtb    = (unsigned short*)carve((size_t)8 * 64 * S_ * 2);
  float*          stc    = (float*)carve((size_t)8 * NC * 65 * 64 * 4);
  unsigned short* stp    = (unsigned short*)carve((size_t)8 * NC * 4096 * 2);
  float*          zp     = (float*)carve((size_t)8 * NC * 64 * 4);
  unsigned short* obuf   = (unsigned short*)carve((size_t)BS_ * D_ * 2);
  float*          o2     = (float*)carve((size_t)BS_ * D_ * 4);

  // P1: all independent prep (x conv, Wk/Wv conv, Wq/Wo transpose, Wc/We prep)
  k_prep<<<3092, 256, 0, stream>>>(x, Wq, Wo, Wk, Wv, Wc, We,
                                   xb, Wqkv_t, Wo_t, Wkv_b, Wc_b, We_t);
  // P2: T = Wc @ We -> Wce (f32) + Wce_t (bf16, transposed)  [M=256,N=256,K=64]
  k_gemm<3><<<dim3(2, 4), 128, 0, stream>>>(Wc_b, We_t, Wce, Wce_t,
                                            256, 64, nullptr, nullptr, nullptr, nullptr);
  // P3: folded K/V weights into Wqkv_t rows [1024,1536) + bias fold (y==4)
  k_gemm<2><<<dim3(16, 5), 128, 0, stream>>>(Wce_t, Wkv_b, Wqkv_t, biasq,
                                             2048, 256, bq, bk, bv, Wce);
  // P4: fused QKV projection -> qkvb bf16 (Q,K pre-featted) [M=2048,N=1536,K=1024]
  k_gemm1<1><<<dim3(24, 32), 64, 0, stream>>>(xb, Wqkv_t, biasq, qkvb, QKVW, 1024);
  // P5: V transpose + per-chunk KV sums
  k_vkv<<<dim3(NC, HKV_, B_), 256, 0, stream>>>(qkvb, vtb, stc);
  // P5b: parallel exclusive chunk-prefix
  k_scan<<<(8 * 65 * 64 + 255) / 256, 256, 0, stream>>>(stc, stp, zp);
  // P6: attention, 2 heads per block
  k_attn<<<dim3(NC, H_ / 2, B_), 512, 0, stream>>>(qkvb, vtb, stp, zp, obuf);
  // P7: output projection [M=2048,N=1024,K=1024]
  k_gemm1<0><<<dim3(16, 32), 64, 0, stream>>>(obuf, Wo_t, bo, o2, 1024, 1024);
  // P8: residual + LayerNorm
  k_ln<<<BS_, 256, 0, stream>>>(x, o2, gamma, beta, (float*)d_out);
}

// Round 8
// 90.919 us; speedup vs baseline: 1.1390x; 1.0724x over previous
//
#include <hip/hip_runtime.h>

#define D_ 1024
#define H_ 16
#define HKV_ 4
#define B_ 2
#define S_ 1024
#define BS_ (B_*S_)
#define QKVW 1536
#define QB 64
#define NC (S_/QB)

typedef short bf8 __attribute__((ext_vector_type(8)));
typedef float f32x4 __attribute__((ext_vector_type(4)));

#define MFMA_B16(a,b,c) __builtin_amdgcn_mfma_f32_16x16x32_bf16((a),(b),(c),0,0,0)

// async global->LDS, 16B per lane; LDS dest must be linear in lane order
#define GLOAD16(g, l) __builtin_amdgcn_global_load_lds( \
    (const __attribute__((address_space(1))) void*)(g), \
    (__attribute__((address_space(3))) void*)(l), 16, 0, 0)

// LDS XOR swizzle for [64][64] bf16 tiles: flips 16B-unit within 8-row stripe.
#define SW(row, idx) ((idx) ^ (((row) & 7) << 3))

__device__ __forceinline__ unsigned short f2b(float f) {
  unsigned int u = __float_as_uint(f);
  u += 0x7FFFu + ((u >> 16) & 1u);
  return (unsigned short)(u >> 16);
}
__device__ __forceinline__ float b2f(unsigned short h) {
  return __uint_as_float(((unsigned int)h) << 16);
}
__device__ __forceinline__ float feat(float x) { return x > 0.f ? x + 1.f : __expf(x); }

// ---------- helpers used by the fused prep kernel ----------
__device__ __forceinline__ void conv_body(const float* __restrict__ src,
                                          unsigned short* __restrict__ dst,
                                          int sub, int n4, int tid) {
  int i = sub * 256 + tid;
  if (i >= n4) return;
  float4 v = ((const float4*)src)[i];
  ushort4 o;
  o.x = f2b(v.x); o.y = f2b(v.y); o.z = f2b(v.z); o.w = f2b(v.w);
  ((ushort4*)dst)[i] = o;
}

__device__ __forceinline__ void tconv_body(const float* __restrict__ src,
                                           unsigned short* __restrict__ dst,
                                           int bx, int by, int ss, int ds,
                                           int tid, float (*tl)[65]) {
  int r0 = by * 64, c0 = bx * 64;
  int ty = tid >> 4, tx4 = (tid & 15) * 4;
#pragma unroll
  for (int rep = 0; rep < 4; ++rep) {
    int r = ty + rep * 16;
    float4 v = *(const float4*)&src[(size_t)(r0 + r) * ss + c0 + tx4];
    tl[r][tx4] = v.x; tl[r][tx4 + 1] = v.y; tl[r][tx4 + 2] = v.z; tl[r][tx4 + 3] = v.w;
  }
  __syncthreads();
#pragma unroll
  for (int rep = 0; rep < 4; ++rep) {
    int c = ty + rep * 16;
    ushort4 o;
    o.x = f2b(tl[tx4 + 0][c]); o.y = f2b(tl[tx4 + 1][c]);
    o.z = f2b(tl[tx4 + 2][c]); o.w = f2b(tl[tx4 + 3][c]);
    *(ushort4*)&dst[(size_t)(c0 + c) * ds + r0 + tx4] = o;
  }
}

// ---------- P1: all independent prep + self-contained Wce GEMM ----------
// blocks 0..2047:    x f32->bf16
// blocks 2048..2303: Wk conv     2304..2559: Wv conv
// blocks 2560..2815: Wq tconv    2816..3071: Wo tconv
// blocks 3072..3079: Wce = Wc @ We (reads f32 directly, reg-staged convert)
__global__ __launch_bounds__(256) void k_prep(const float* __restrict__ x,
                                              const float* __restrict__ Wq,
                                              const float* __restrict__ Wo,
                                              const float* __restrict__ Wk,
                                              const float* __restrict__ Wv,
                                              const float* __restrict__ Wc,
                                              const float* __restrict__ We,
                                              unsigned short* __restrict__ xb,
                                              unsigned short* __restrict__ Wqkv_t,
                                              unsigned short* __restrict__ Wo_t,
                                              unsigned short* __restrict__ Wkv_b,
                                              float* __restrict__ Wce,
                                              unsigned short* __restrict__ Wce_t) {
  __shared__ float tl[64][65];
  __shared__ __align__(16) unsigned short As[64][72];
  __shared__ __align__(16) unsigned short Bs[128][72];
  int blk = blockIdx.x, tid = threadIdx.x;
  if (blk < 2048) {
    conv_body(x, xb, blk, BS_ * D_ / 4, tid);
  } else if (blk < 2304) {
    conv_body(Wk, Wkv_b, blk - 2048, 1024 * 256 / 4, tid);
  } else if (blk < 2560) {
    conv_body(Wv, Wkv_b + 1024 * 256, blk - 2304, 1024 * 256 / 4, tid);
  } else if (blk < 2816) {
    int sb = blk - 2560;
    tconv_body(Wq, Wqkv_t, sb & 15, sb >> 4, 1024, 1024, tid, tl);
  } else if (blk < 3072) {
    int sb = blk - 2816;
    tconv_body(Wo, Wo_t, sb & 15, sb >> 4, 1024, 1024, tid, tl);
  } else {
    // ---- Wce[256,256] = Wc[256,64] @ We[64,256]; also Wce_t = Wce^T bf16 ----
    int sb = blk - 3072;
    int row0 = (sb >> 1) * 64, col0 = (sb & 1) * 128;
    {
      // As[r][k] = bf16(Wc[row0+r][k]), r<64, k<64
      int r = tid >> 2, c0 = (tid & 3) * 16;
      const float* src = &Wc[(size_t)(row0 + r) * 64 + c0];
#pragma unroll
      for (int e = 0; e < 16; e += 4) {
        float4 v = *(const float4*)(src + e);
        As[r][c0 + e] = f2b(v.x); As[r][c0 + e + 1] = f2b(v.y);
        As[r][c0 + e + 2] = f2b(v.z); As[r][c0 + e + 3] = f2b(v.w);
      }
      // Bs[c][k] = bf16(We[k][col0+c]), c<128, k<64 (transpose on LDS write)
      int k = tid >> 2, cb = (tid & 3) * 32;
      const float* wsrc = &We[(size_t)k * 256 + col0 + cb];
#pragma unroll
      for (int e = 0; e < 32; e += 4) {
        float4 v = *(const float4*)(wsrc + e);
        Bs[cb + e][k] = f2b(v.x); Bs[cb + e + 1][k] = f2b(v.y);
        Bs[cb + e + 2][k] = f2b(v.z); Bs[cb + e + 3][k] = f2b(v.w);
      }
    }
    __syncthreads();
    const int lane = tid & 63, wave = tid >> 6;
    const int lr = lane & 15, lq = lane >> 4;
    const int wc0 = wave * 32;
    const f32x4 fzero = {0.f, 0.f, 0.f, 0.f};
    f32x4 acc[4][2];
#pragma unroll
    for (int i = 0; i < 4; ++i) { acc[i][0] = fzero; acc[i][1] = fzero; }
#pragma unroll
    for (int kk = 0; kk < 2; ++kk)
#pragma unroll
      for (int mi = 0; mi < 4; ++mi) {
        bf8 a = *(const bf8*)&As[mi * 16 + lr][kk * 32 + lq * 8];
#pragma unroll
        for (int ni = 0; ni < 2; ++ni) {
          bf8 bb = *(const bf8*)&Bs[wc0 + ni * 16 + lr][kk * 32 + lq * 8];
          acc[mi][ni] = MFMA_B16(a, bb, acc[mi][ni]);
        }
      }
#pragma unroll
    for (int mi = 0; mi < 4; ++mi)
#pragma unroll
      for (int ni = 0; ni < 2; ++ni) {
        int col = col0 + wc0 + ni * 16 + lr;
#pragma unroll
        for (int r = 0; r < 4; ++r) {
          int row = row0 + mi * 16 + lq * 4 + r;
          float v = acc[mi][ni][r];
          Wce[(size_t)row * 256 + col] = v;
          Wce_t[(size_t)col * 256 + row] = f2b(v);
        }
      }
  }
}

// ---------- 1-wave 64x64 bt-GEMM: no barriers, dbuf LDS, BK=64, counted vmcnt ----
// MODE 0: bf16 out + bias (O-proj);  MODE 1: bf16 out + bias + feat col<1280 (QKV)
// 16B-chunk XOR swizzle on BOTH global_load_lds source and ds_read.
template<int MODE>
__global__ __launch_bounds__(64) void k_gemm1(const unsigned short* __restrict__ A,
                                              const unsigned short* __restrict__ Bt,
                                              const float* __restrict__ bias,
                                              unsigned short* __restrict__ C,
                                              int N, int K) {
  __shared__ __align__(16) unsigned short As[2][64 * 64];
  __shared__ __align__(16) unsigned short Bs[2][64 * 64];
  const int lane = threadIdx.x;
  const int row0 = blockIdx.y * 64, col0 = blockIdx.x * 64;
  const int lr = lane & 15, lq = lane >> 4;
  const int rsub = lane >> 3, sj = lane & 7;
  const int js = sj ^ rsub;            // swizzled chunk, loop-invariant
  const f32x4 fzero = {0.f, 0.f, 0.f, 0.f};
  f32x4 acc[4][4];
#pragma unroll
  for (int i = 0; i < 4; ++i)
#pragma unroll
    for (int j = 0; j < 4; ++j) acc[i][j] = fzero;

#define STAGE64(pb, k0)                                                        \
  {                                                                            \
    _Pragma("unroll")                                                          \
    for (int i = 0; i < 8; ++i)                                                \
      GLOAD16(&A[(size_t)(row0 + i * 8 + rsub) * K + (k0) + js * 8],           \
              &As[pb][(i * 512 + lane * 8)]);                                  \
    _Pragma("unroll")                                                          \
    for (int i = 0; i < 8; ++i)                                                \
      GLOAD16(&Bt[(size_t)(col0 + i * 8 + rsub) * K + (k0) + js * 8],          \
              &Bs[pb][(i * 512 + lane * 8)]);                                  \
  }

  STAGE64(0, 0);
  int cur = 0;
  for (int k0 = 0; k0 < K; k0 += 64) {
    if (k0 + 64 < K) {
      STAGE64(cur ^ 1, k0 + 64);
      asm volatile("s_waitcnt vmcnt(16)" ::: "memory");  // prev buffer drained
    } else {
      asm volatile("s_waitcnt vmcnt(0)" ::: "memory");
    }
    __builtin_amdgcn_sched_barrier(0);
    bf8 af[2][4], bfr[2][4];
#pragma unroll
    for (int kk = 0; kk < 2; ++kk)
#pragma unroll
      for (int mi = 0; mi < 4; ++mi) {
        int ch = (kk * 4 + lq) ^ (lr & 7);
        af[kk][mi]  = *(const bf8*)&As[cur][(mi * 16 + lr) * 64 + ch * 8];
        bfr[kk][mi] = *(const bf8*)&Bs[cur][(mi * 16 + lr) * 64 + ch * 8];
      }
#pragma unroll
    for (int kk = 0; kk < 2; ++kk)
#pragma unroll
      for (int mi = 0; mi < 4; ++mi)
#pragma unroll
        for (int ni = 0; ni < 4; ++ni)
          acc[mi][ni] = MFMA_B16(af[kk][mi], bfr[kk][ni], acc[mi][ni]);
    cur ^= 1;
  }
#undef STAGE64
#pragma unroll
  for (int ni = 0; ni < 4; ++ni) {
    int col = col0 + ni * 16 + lr;
    float bv = bias[col];
#pragma unroll
    for (int mi = 0; mi < 4; ++mi)
#pragma unroll
      for (int r = 0; r < 4; ++r) {
        int row = row0 + mi * 16 + lq * 4 + r;
        float v = acc[mi][ni][r] + bv;
        if (MODE == 1 && col < 1280) v = feat(v);
        C[(size_t)row * N + col] = f2b(v);
      }
  }
}

// ---------- weight-fold bt-GEMM (P3), 64x128 tile, 2 waves ----------
// foldKV bf16 remap out; blockIdx.y==4 -> fused bias fold
__global__ __launch_bounds__(128) void k_fold(const unsigned short* __restrict__ A,
                                              const unsigned short* __restrict__ Bt,
                                              unsigned short* __restrict__ C,
                                              float* __restrict__ biasq,
                                              int N, int K,
                                              const float* __restrict__ fbq,
                                              const float* __restrict__ fbk,
                                              const float* __restrict__ fbv,
                                              const float* __restrict__ fWce) {
  if (blockIdx.y == 4) {
    int t = blockIdx.x * 128 + threadIdx.x;
    if (t >= QKVW) return;
    if (t < 1024) { biasq[t] = fbq[t]; return; }
    const float* b = (t < 1280) ? fbk : fbv;
    int n = (t < 1280) ? (t - 1024) : (t - 1280);
    float s = 0.f;
    for (int j = 0; j < 256; ++j) s += b[j] * fWce[j * 256 + n];
    biasq[t] = s;
    return;
  }
  __shared__ __align__(16) unsigned short As[64 * 32];
  __shared__ __align__(16) unsigned short Bs[128 * 32];
  const int tid = threadIdx.x;
  const int lane = tid & 63, wave = tid >> 6;
  const int row0 = blockIdx.y * 64, col0 = blockIdx.x * 128;
  const f32x4 fzero = {0.f, 0.f, 0.f, 0.f};
  f32x4 acc[4][4];
#pragma unroll
  for (int i = 0; i < 4; ++i)
#pragma unroll
    for (int j = 0; j < 4; ++j) acc[i][j] = fzero;
  const int lr = lane & 15, lq = lane >> 4, lk = lq * 8;
  for (int k0 = 0; k0 < K; k0 += 32) {
#pragma unroll
    for (int i = 0; i < 2; ++i) {
      int e = (tid + i * 128) * 8;
      int r = e >> 5, c = e & 31;
      GLOAD16(&A[(size_t)(row0 + r) * K + k0 + c], &As[e]);
    }
#pragma unroll
    for (int i = 0; i < 4; ++i) {
      int e = (tid + i * 128) * 8;
      int r = e >> 5, c = e & 31;
      GLOAD16(&Bt[(size_t)(col0 + r) * K + k0 + c], &Bs[e]);
    }
    __syncthreads();
    bf8 af[4], bfr[4];
#pragma unroll
    for (int mi = 0; mi < 4; ++mi)
      af[mi] = *(const bf8*)&As[(mi * 16 + lr) * 32 + lk];
#pragma unroll
    for (int ni = 0; ni < 4; ++ni)
      bfr[ni] = *(const bf8*)&Bs[(wave * 64 + ni * 16 + lr) * 32 + lk];
#pragma unroll
    for (int mi = 0; mi < 4; ++mi)
#pragma unroll
      for (int ni = 0; ni < 4; ++ni)
        acc[mi][ni] = MFMA_B16(af[mi], bfr[ni], acc[mi][ni]);
    __syncthreads();
  }
#pragma unroll
  for (int mi = 0; mi < 4; ++mi)
#pragma unroll
    for (int ni = 0; ni < 4; ++ni) {
      int col = col0 + wave * 64 + ni * 16 + lr;
#pragma unroll
      for (int r = 0; r < 4; ++r) {
        int row = row0 + mi * 16 + lq * 4 + r;
        int sec = col >> 10, cc = col & 1023;
        C[(size_t)(1024 + sec * 256 + row) * 1024 + cc] = f2b(acc[mi][ni][r]);
      }
    }
}

// ---------- fused V-transpose + per-chunk KV sums (qkvb bf16, K pre-featted) ----------
__global__ __launch_bounds__(256) void k_vkv(const unsigned short* __restrict__ qkvb,
                                             unsigned short* __restrict__ vt,
                                             float* __restrict__ stc) {
  __shared__ unsigned short tl[64][72];   // V^T staging (raw bf16)
  __shared__ float Kf[64 * 64];
  int c = blockIdx.x, g = blockIdx.y, b = blockIdx.z;
  int tid = threadIdx.x;
  int s0 = c * QB;
  {
    int j = tid >> 2, f0 = (tid & 3) * 16;
    const unsigned short* kr = &qkvb[(size_t)(b * S_ + s0 + j) * QKVW + 1024 + g * 64 + f0];
    const unsigned short* vr = &qkvb[(size_t)(b * S_ + s0 + j) * QKVW + 1280 + g * 64 + f0];
    uint4 k0_ = *(const uint4*)kr;
    uint4 k1_ = *(const uint4*)(kr + 8);
    const unsigned short* ks = (const unsigned short*)&k0_;
#pragma unroll
    for (int e = 0; e < 8; ++e) Kf[j * 64 + f0 + e] = b2f(ks[e]);
    ks = (const unsigned short*)&k1_;
#pragma unroll
    for (int e = 0; e < 8; ++e) Kf[j * 64 + f0 + 8 + e] = b2f(ks[e]);
    *(uint4*)&tl[j][f0] = *(const uint4*)vr;
    *(uint4*)&tl[j][f0 + 8] = *(const uint4*)(vr + 8);
  }
  __syncthreads();
  // write vt[b][g][d][s] bf16
  {
    int ty = tid >> 4, tx4 = (tid & 15) * 4;
#pragma unroll
    for (int rep = 0; rep < 4; ++rep) {
      int d = ty + rep * 16;
      ushort4 o;
      o.x = tl[tx4 + 0][d]; o.y = tl[tx4 + 1][d];
      o.z = tl[tx4 + 2][d]; o.w = tl[tx4 + 3][d];
      *(ushort4*)&vt[((size_t)(b * HKV_ + g) * 64 + d) * S_ + s0 + tx4] = o;
    }
  }
  // per-chunk sums St_c[d][f] and z_c[f]
  int d = tid >> 2, f0 = (tid & 3) * 16;
  float acc[16];
#pragma unroll
  for (int e = 0; e < 16; ++e) acc[e] = 0.f;
#pragma unroll 4
  for (int j = 0; j < QB; ++j) {
    float vv = b2f(tl[j][d]);
    const float* kfr = &Kf[j * 64 + f0];
#pragma unroll
    for (int e = 0; e < 16; ++e) acc[e] += vv * kfr[e];
  }
  size_t base = ((size_t)((b * HKV_ + g) * NC + c) * 65 + d) * 64 + f0;
#pragma unroll
  for (int e = 0; e < 16; ++e) stc[base + e] = acc[e];
  if (tid < 64) {
    float z = 0.f;
    for (int j = 0; j < QB; ++j) z += Kf[j * 64 + tid];
    stc[((size_t)((b * HKV_ + g) * NC + c) * 65 + 64) * 64 + tid] = z;
  }
}

// ------- exclusive prefix over chunks — one thread per element, TLP-hidden -------
__global__ __launch_bounds__(256) void k_scan(const float* __restrict__ stc,
                                              unsigned short* __restrict__ stp,
                                              float* __restrict__ zp) {
  int t = blockIdx.x * 256 + threadIdx.x;
  if (t >= 8 * 65 * 64) return;
  int bg = t / (65 * 64);
  int e = t - bg * (65 * 64);
  int d = e >> 6, f = e & 63;
  float run = 0.f;
#pragma unroll
  for (int c = 0; c < NC; ++c) {
    if (d < 64) stp[(size_t)(bg * NC + c) * 4096 + e] = f2b(run);
    else        zp[(bg * NC + c) * 64 + f] = run;
    run += stc[((size_t)(bg * NC + c) * 65 + d) * 64 + f];
  }
}

// ---------- per-(chunk, head-pair) attention; 2 heads share K/V/S/z loads ----------
__global__ __launch_bounds__(512) void k_attn(const unsigned short* __restrict__ qkvb,
                                              const unsigned short* __restrict__ vt,
                                              const unsigned short* __restrict__ stp,
                                              const float* __restrict__ zp,
                                              unsigned short* __restrict__ ob) {
  __shared__ __align__(16) unsigned short Qf[2][64 * 64];
  __shared__ __align__(16) unsigned short Kf[64 * 64];
  __shared__ __align__(16) unsigned short Vl[64 * 64];
  __shared__ __align__(16) unsigned short Sl[64 * 64];
  __shared__ __align__(16) unsigned short P[2][64 * 64];
  __shared__ __align__(16) unsigned short Ol[64][144];
  __shared__ float zl[64];
  __shared__ float den[2][64];
  int c = blockIdx.x, hp = blockIdx.y, b = blockIdx.z;
  int g = hp >> 1;
  int tid = threadIdx.x, lane = tid & 63, wave = tid >> 6;
  int s0 = c * QB;
  {
    int hsel = tid >> 8, t = tid & 255;
    int j = t >> 2, f0 = (t & 3) * 16;
    const unsigned short* qr =
        &qkvb[(size_t)(b * S_ + s0 + j) * QKVW + (hp * 2 + hsel) * 64 + f0];
    *(uint4*)&Qf[hsel][SW(j, j * 64 + f0)]     = *(const uint4*)qr;
    *(uint4*)&Qf[hsel][SW(j, j * 64 + f0 + 8)] = *(const uint4*)(qr + 8);
    if (tid < 256) {
      const unsigned short* kr =
          &qkvb[(size_t)(b * S_ + s0 + j) * QKVW + 1024 + g * 64 + f0];
      *(uint4*)&Kf[SW(j, j * 64 + f0)]     = *(const uint4*)kr;
      *(uint4*)&Kf[SW(j, j * 64 + f0 + 8)] = *(const uint4*)(kr + 8);
    } else {
      const unsigned short* vbase = &vt[((size_t)(b * HKV_ + g) * 64) * S_ + s0];
#pragma unroll
      for (int i2 = 0; i2 < 2; ++i2) {
        int cc = t * 2 + i2;
        int dd = cc >> 3, col = (cc & 7) * 8;
        *(uint4*)&Vl[SW(dd, cc * 8)] = *(const uint4*)&vbase[(size_t)dd * S_ + col];
      }
    }
    const unsigned short* sbase = &stp[(size_t)((b * HKV_ + g) * NC + c) * 4096];
    { int dd = tid >> 3; *(uint4*)&Sl[SW(dd, tid * 8)] = *(const uint4*)&sbase[tid * 8]; }
    if (tid < 64) zl[tid] = zp[((b * HKV_ + g) * NC + c) * 64 + tid];
  }
  __syncthreads();
  const int lr = lane & 15, lq = lane >> 4, lk = lq * 8;
  const int hh = wave >> 2, rw = (wave & 3) * 16;
  const f32x4 fzero = {0.f, 0.f, 0.f, 0.f};
  bf8 aQ[2];
#pragma unroll
  for (int kk = 0; kk < 2; ++kk)
    aQ[kk] = *(const bf8*)&Qf[hh][SW(rw + lr, (rw + lr) * 64 + kk * 32 + lk)];
  f32x4 sc[4];
#pragma unroll
  for (int nj = 0; nj < 4; ++nj) sc[nj] = fzero;
#pragma unroll
  for (int nj = 0; nj < 4; ++nj)
#pragma unroll
    for (int kk = 0; kk < 2; ++kk) {
      bf8 bk8 = *(const bf8*)&Kf[SW(nj * 16 + lr, (nj * 16 + lr) * 64 + kk * 32 + lk)];
      sc[nj] = MFMA_B16(aQ[kk], bk8, sc[nj]);
    }
#pragma unroll
  for (int nj = 0; nj < 4; ++nj)
#pragma unroll
    for (int r = 0; r < 4; ++r) {
      int i = rw + lq * 4 + r;
      int j = nj * 16 + lr;
      float v = (j <= i) ? sc[nj][r] : 0.f;
      P[hh][SW(i, i * 64 + j)] = f2b(v);
    }
  __syncthreads();
  {
    int hd = tid >> 8, t = tid & 255;
    int i = t >> 2, q = t & 3, f0 = q * 16;
    float s = 0.f;
#pragma unroll
    for (int e = 0; e < 16; ++e) s += b2f(P[hd][SW(i, i * 64 + f0 + e)]);
#pragma unroll
    for (int e = 0; e < 16; ++e) s += b2f(Qf[hd][SW(i, i * 64 + f0 + e)]) * zl[f0 + e];
    s += __shfl_xor(s, 1);
    s += __shfl_xor(s, 2);
    if (q == 0) den[hd][i] = s;
  }
  f32x4 oa[4];
#pragma unroll
  for (int nd = 0; nd < 4; ++nd) oa[nd] = fzero;
  bf8 aP[2];
#pragma unroll
  for (int kk = 0; kk < 2; ++kk)
    aP[kk] = *(const bf8*)&P[hh][SW(rw + lr, (rw + lr) * 64 + kk * 32 + lk)];
#pragma unroll
  for (int nd = 0; nd < 4; ++nd)
#pragma unroll
    for (int kk = 0; kk < 2; ++kk) {
      bf8 bS = *(const bf8*)&Sl[SW(nd * 16 + lr, (nd * 16 + lr) * 64 + kk * 32 + lk)];
      oa[nd] = MFMA_B16(aQ[kk], bS, oa[nd]);
      bf8 bV = *(const bf8*)&Vl[SW(nd * 16 + lr, (nd * 16 + lr) * 64 + kk * 32 + lk)];
      oa[nd] = MFMA_B16(aP[kk], bV, oa[nd]);
    }
  __syncthreads();
#pragma unroll
  for (int nd = 0; nd < 4; ++nd)
#pragma unroll
    for (int r = 0; r < 4; ++r) {
      int i = rw + lq * 4 + r;
      int dd = nd * 16 + lr;
      Ol[i][hh * 64 + dd] = f2b(oa[nd][r] / (den[hh][i] + 1e-6f));
    }
  __syncthreads();
  {
    int j = tid >> 3, u = tid & 7;
    unsigned short* orow = &ob[(size_t)(b * S_ + s0 + j) * D_ + hp * 128 + u * 16];
    *(uint4*)orow       = *(const uint4*)&Ol[j][u * 16];
    *(uint4*)(orow + 8) = *(const uint4*)&Ol[j][u * 16 + 8];
  }
}

// ------- residual + LayerNorm (bf16 x, bf16 o2) -------
__global__ __launch_bounds__(256) void k_ln(const unsigned short* __restrict__ xb,
                                            const unsigned short* __restrict__ o2,
                                            const float* __restrict__ gamma,
                                            const float* __restrict__ beta,
                                            float* __restrict__ out) {
  int row = blockIdx.x, tid = threadIdx.x;
  ushort4 xv = ((const ushort4*)(xb + (size_t)row * D_))[tid];
  ushort4 ov = ((const ushort4*)(o2 + (size_t)row * D_))[tid];
  float4 y;
  y.x = b2f(xv.x) + b2f(ov.x); y.y = b2f(xv.y) + b2f(ov.y);
  y.z = b2f(xv.z) + b2f(ov.z); y.w = b2f(xv.w) + b2f(ov.w);
  float s = y.x + y.y + y.z + y.w;
  float ss = y.x * y.x + y.y * y.y + y.z * y.z + y.w * y.w;
#pragma unroll
  for (int off = 32; off > 0; off >>= 1) {
    s += __shfl_down(s, off);
    ss += __shfl_down(ss, off);
  }
  __shared__ float red[8];
  int lane = tid & 63, wave = tid >> 6;
  if (lane == 0) { red[wave] = s; red[4 + wave] = ss; }
  __syncthreads();
  if (tid == 0) {
    red[0] = red[0] + red[1] + red[2] + red[3];
    red[4] = red[4] + red[5] + red[6] + red[7];
  }
  __syncthreads();
  float mu = red[0] * (1.f / D_);
  float var = red[4] * (1.f / D_) - mu * mu;
  float rs = rsqrtf(var + 1e-5f);
  float4 g4 = ((const float4*)gamma)[tid];
  float4 b4 = ((const float4*)beta)[tid];
  float4 o;
  o.x = (y.x - mu) * rs * g4.x + b4.x;
  o.y = (y.y - mu) * rs * g4.y + b4.y;
  o.z = (y.z - mu) * rs * g4.z + b4.z;
  o.w = (y.w - mu) * rs * g4.w + b4.w;
  ((float4*)(out + (size_t)row * D_))[tid] = o;
}

extern "C" void kernel_launch(void* const* d_in, const int* in_sizes, int n_in,
                              void* d_out, int out_size, void* d_ws, size_t ws_size,
                              hipStream_t stream) {
  const float* x     = (const float*)d_in[0];
  const float* Wq    = (const float*)d_in[1];
  const float* bq    = (const float*)d_in[2];
  const float* Wk    = (const float*)d_in[3];
  const float* bk    = (const float*)d_in[4];
  const float* Wv    = (const float*)d_in[5];
  const float* bv    = (const float*)d_in[6];
  const float* Wc    = (const float*)d_in[7];
  const float* We    = (const float*)d_in[8];
  const float* Wo    = (const float*)d_in[9];
  const float* bo    = (const float*)d_in[10];
  const float* gamma = (const float*)d_in[11];
  const float* beta  = (const float*)d_in[12];

  char* p = (char*)d_ws;
  size_t off = 0;
  auto carve = [&](size_t bytes) {
    void* r = p + off;
    off = (off + bytes + 255) & ~(size_t)255;
    return r;
  };
  unsigned short* xb     = (unsigned short*)carve((size_t)BS_ * D_ * 2);
  unsigned short* Wqkv_t = (unsigned short*)carve((size_t)QKVW * D_ * 2);
  unsigned short* Wo_t   = (unsigned short*)carve((size_t)D_ * D_ * 2);
  float*          biasq  = (float*)carve(QKVW * 4);
  unsigned short* qkvb   = (unsigned short*)carve((size_t)BS_ * QKVW * 2);
  float*          Wce    = (float*)carve(256 * 256 * 4);
  unsigned short* Wce_t  = (unsigned short*)carve(256 * 256 * 2);
  unsigned short* Wkv_b  = (unsigned short*)carve((size_t)2048 * 256 * 2);
  unsigned short* vtb    = (unsigned short*)carve((size_t)8 * 64 * S_ * 2);
  float*          stc    = (float*)carve((size_t)8 * NC * 65 * 64 * 4);
  unsigned short* stp    = (unsigned short*)carve((size_t)8 * NC * 4096 * 2);
  float*          zp     = (float*)carve((size_t)8 * NC * 64 * 4);
  unsigned short* obuf   = (unsigned short*)carve((size_t)BS_ * D_ * 2);
  unsigned short* o2     = (unsigned short*)carve((size_t)BS_ * D_ * 2);

  // P1: prep + self-contained Wce GEMM (8 extra blocks)
  k_prep<<<3080, 256, 0, stream>>>(x, Wq, Wo, Wk, Wv, Wc, We,
                                   xb, Wqkv_t, Wo_t, Wkv_b, Wce, Wce_t);
  // P3: folded K/V weights into Wqkv_t rows [1024,1536) + bias fold (y==4)
  k_fold<<<dim3(16, 5), 128, 0, stream>>>(Wce_t, Wkv_b, Wqkv_t, biasq,
                                          2048, 256, bq, bk, bv, Wce);
  // P4: fused QKV projection -> qkvb bf16 (Q,K pre-featted) [2048,1536,K=1024]
  k_gemm1<1><<<dim3(24, 32), 64, 0, stream>>>(xb, Wqkv_t, biasq, qkvb, QKVW, 1024);
  // P5: V transpose + per-chunk KV sums
  k_vkv<<<dim3(NC, HKV_, B_), 256, 0, stream>>>(qkvb, vtb, stc);
  // P5b: parallel exclusive chunk-prefix
  k_scan<<<(8 * 65 * 64 + 255) / 256, 256, 0, stream>>>(stc, stp, zp);
  // P6: attention, 2 heads per block
  k_attn<<<dim3(NC, H_ / 2, B_), 512, 0, stream>>>(qkvb, vtb, stp, zp, obuf);
  // P7: output projection -> o2 bf16 [2048,1024,K=1024]
  k_gemm1<0><<<dim3(16, 32), 64, 0, stream>>>(obuf, Wo_t, bo, o2, 1024, 1024);
  // P8: residual + LayerNorm (bf16 inputs)
  k_ln<<<BS_, 256, 0, stream>>>(xb, o2, gamma, beta, (float*)d_out);
}